// Round 2
// baseline (667.318 us; speedup 1.0000x reference)
//
#include <hip/hip_runtime.h>

// Problem constants (B, L, D, H) = (16, 512, 128, 8)
#define B_  16
#define L_  512
#define D_  128
#define H_  8
#define HD_ 1024   // H*D
#define NH_ 128    // H*B
#define M_  8192   // B*L

// ---------- bf16 helpers (raw ushort representation) ----------
__device__ __forceinline__ float bf2f(unsigned short u) {
    union { unsigned u; float f; } x; x.u = ((unsigned)u) << 16; return x.f;
}
__device__ __forceinline__ unsigned short f2bf(float f) {
    unsigned u = __float_as_uint(f);
    unsigned r = (u + 0x7FFFu + ((u >> 16) & 1u)) >> 16;   // RNE
    return (unsigned short)r;
}

// ---------- dtype-switched accessors (dt: 1 = bf16, 0 = fp32) ----------
__device__ __forceinline__ float4 ld4(const void* p, size_t idx, int dt) {
    if (dt) {
        ushort4 v = *(const ushort4*)((const unsigned short*)p + idx);
        return make_float4(bf2f(v.x), bf2f(v.y), bf2f(v.z), bf2f(v.w));
    }
    return *(const float4*)((const float*)p + idx);
}
__device__ __forceinline__ float ld1(const void* p, size_t idx, int dt) {
    if (dt) return bf2f(((const unsigned short*)p)[idx]);
    return ((const float*)p)[idx];
}
__device__ __forceinline__ void st1(void* p, size_t idx, float v, int dt) {
    if (dt) ((unsigned short*)p)[idx] = f2bf(v);
    else    ((float*)p)[idx] = v;
}

// ---------------------------------------------------------------
// 64x64-tile fp32-accumulate GEMM cores, 256 threads, 4x4 micro-tile,
// K staged in chunks of 16 through LDS.
// bt: C = A @ B^T   (A [*,K] row-major, B [*,K] row-major)
// bn: C = A @ B     (A [*,K] row-major, B [K,*] row-major)
// Caller pre-offsets A/B to the tile origin. K % 16 == 0.
// ---------------------------------------------------------------
__device__ __forceinline__ void gemm_bt_core(const void* __restrict__ A, int lda, int dtA,
                                             const void* __restrict__ Bt, int ldb, int dtB,
                                             int K, float acc[4][4]) {
    __shared__ float As[16][64];
    __shared__ float Bs[16][64];
    const int tid = threadIdx.x;
    const int tx = tid & 15, ty = tid >> 4;
    const int lr = tid >> 2;          // 0..63 (tile row)
    const int lk = (tid & 3) << 2;    // 0,4,8,12 (k offset)
    for (int k0 = 0; k0 < K; k0 += 16) {
        float4 av = ld4(A,  (size_t)lr * lda + k0 + lk, dtA);
        float4 bv = ld4(Bt, (size_t)lr * ldb + k0 + lk, dtB);
        __syncthreads();
        As[lk+0][lr] = av.x; As[lk+1][lr] = av.y;
        As[lk+2][lr] = av.z; As[lk+3][lr] = av.w;
        Bs[lk+0][lr] = bv.x; Bs[lk+1][lr] = bv.y;
        Bs[lk+2][lr] = bv.z; Bs[lk+3][lr] = bv.w;
        __syncthreads();
#pragma unroll
        for (int kk = 0; kk < 16; kk++) {
            float4 a = *(const float4*)&As[kk][ty << 2];
            float4 b = *(const float4*)&Bs[kk][tx << 2];
            acc[0][0] += a.x*b.x; acc[0][1] += a.x*b.y; acc[0][2] += a.x*b.z; acc[0][3] += a.x*b.w;
            acc[1][0] += a.y*b.x; acc[1][1] += a.y*b.y; acc[1][2] += a.y*b.z; acc[1][3] += a.y*b.w;
            acc[2][0] += a.z*b.x; acc[2][1] += a.z*b.y; acc[2][2] += a.z*b.z; acc[2][3] += a.z*b.w;
            acc[3][0] += a.w*b.x; acc[3][1] += a.w*b.y; acc[3][2] += a.w*b.z; acc[3][3] += a.w*b.w;
        }
    }
}

__device__ __forceinline__ void gemm_bn_core(const void* __restrict__ A, int lda, int dtA,
                                             const void* __restrict__ Bn, int ldb, int dtB,
                                             int K, float acc[4][4]) {
    __shared__ float As[16][64];
    __shared__ float Bs[16][64];
    const int tid = threadIdx.x;
    const int tx = tid & 15, ty = tid >> 4;
    const int lr = tid >> 2;          // A loader: row 0..63, k chunk of 4
    const int lk = (tid & 3) << 2;
    const int br = tid >> 4;          // B loader: k row 0..15
    const int bc = (tid & 15) << 2;   // col 0..60
    for (int k0 = 0; k0 < K; k0 += 16) {
        float4 av = ld4(A,  (size_t)lr * lda + k0 + lk, dtA);
        float4 bv = ld4(Bn, (size_t)(k0 + br) * ldb + bc, dtB);
        __syncthreads();
        As[lk+0][lr] = av.x; As[lk+1][lr] = av.y;
        As[lk+2][lr] = av.z; As[lk+3][lr] = av.w;
        Bs[br][bc+0] = bv.x; Bs[br][bc+1] = bv.y;
        Bs[br][bc+2] = bv.z; Bs[br][bc+3] = bv.w;
        __syncthreads();
#pragma unroll
        for (int kk = 0; kk < 16; kk++) {
            float4 a = *(const float4*)&As[kk][ty << 2];
            float4 b = *(const float4*)&Bs[kk][tx << 2];
            acc[0][0] += a.x*b.x; acc[0][1] += a.x*b.y; acc[0][2] += a.x*b.z; acc[0][3] += a.x*b.w;
            acc[1][0] += a.y*b.x; acc[1][1] += a.y*b.y; acc[1][2] += a.y*b.z; acc[1][3] += a.y*b.w;
            acc[2][0] += a.z*b.x; acc[2][1] += a.z*b.y; acc[2][2] += a.z*b.z; acc[2][3] += a.z*b.w;
            acc[3][0] += a.w*b.x; acc[3][1] += a.w*b.y; acc[3][2] += a.w*b.z; acc[3][3] += a.w*b.w;
        }
    }
}

// ---------------------------------------------------------------
// K0: detect (a) float dtype of x: fp32 vs packed bf16, and
//            (b) pad_mask storage: int32 0/1 vs packed uint8 bool.
// For fp32 data, bits 14..7 of each 32-bit word are mantissa noise
// (uniform; ~12% land in [100,131]).  For packed-bf16 N(0,1) data they
// are a real bf16 exponent field (~100% in [100,131]).
// flags[0] = 1 if floats are bf16; flags[1] = 1 if mask is uint8.
// ---------------------------------------------------------------
__global__ void k0_detect(const unsigned int* __restrict__ pad,
                          const unsigned int* __restrict__ xw,
                          int* __restrict__ flags) {
    __shared__ int sMask, sCnt;
    if (threadIdx.x == 0) { sMask = 0; sCnt = 0; }
    __syncthreads();
    int bad = 0;
#pragma unroll
    for (int i = 0; i < 4; i++) {
        unsigned u = pad[threadIdx.x * 4 + i];   // first 4 KiB — in bounds either way
        bad |= (u > 1u) ? 1 : 0;
    }
    int cnt = 0;
#pragma unroll
    for (int i = 0; i < 16; i++) {
        unsigned w = xw[threadIdx.x * 16 + i];   // first 16 KiB of x
        unsigned e = (w >> 7) & 0xFFu;
        cnt += (e >= 100u && e <= 131u) ? 1 : 0;
    }
    if (bad) atomicOr(&sMask, 1);
    atomicAdd(&sCnt, cnt);
    __syncthreads();
    if (threadIdx.x == 0) {
        flags[0] = (sCnt > 2048) ? 1 : 0;
        flags[1] = sMask;
    }
}

// ---------------------------------------------------------------
// K1: q/k/v projection.  y = x @ W^T + b, written head-major [H*B, L, D]
// Intermediates stored bf16.  grid (HD/64, M/64, 3)
// ---------------------------------------------------------------
__global__ __launch_bounds__(256) void k1_proj(
    const void* __restrict__ x,
    const void* __restrict__ Wq, const void* __restrict__ bq,
    const void* __restrict__ Wk, const void* __restrict__ bk,
    const void* __restrict__ Wv, const void* __restrict__ bv,
    const int* __restrict__ flags,
    unsigned short* __restrict__ qb, unsigned short* __restrict__ kb,
    unsigned short* __restrict__ vb) {
    const int dt = flags[0];
    const int n0 = blockIdx.x * 64;   // e (=h*D+d) tile
    const int m0 = blockIdx.y * 64;   // row (=b*L+l) tile
    const int z  = blockIdx.z;
    const void* W    = (z == 0) ? Wq : (z == 1) ? Wk : Wv;
    const void* bias = (z == 0) ? bq : (z == 1) ? bk : bv;
    unsigned short* out = (z == 0) ? qb : (z == 1) ? kb : vb;

    float acc[4][4] = {};
    const unsigned short* Ab = (const unsigned short*)x;  // element offset math below
    gemm_bt_core(dt ? (const void*)(Ab + (size_t)m0 * D_) : (const void*)((const float*)x + (size_t)m0 * D_),
                 D_, dt,
                 dt ? (const void*)((const unsigned short*)W + (size_t)n0 * D_)
                    : (const void*)((const float*)W + (size_t)n0 * D_),
                 D_, dt, D_, acc);

    const int tx = threadIdx.x & 15, ty = threadIdx.x >> 4;
#pragma unroll
    for (int i = 0; i < 4; i++) {
        int m = m0 + ty * 4 + i;
        int bb = m >> 9, l = m & 511;          // m = b*L + l, L=512
#pragma unroll
        for (int j = 0; j < 4; j++) {
            int e = n0 + tx * 4 + j;
            float v = acc[i][j] + ld1(bias, e, dt);
            int h = e >> 7, d = e & 127;       // e = h*D + d, D=128
            out[((size_t)(h * B_ + bb) * L_ + l) * D_ + d] = f2bf(v);
        }
    }
}

// ---------------------------------------------------------------
// K2: scores s[n,q,k] = (mask[b,q,k] ? -1e9 : q.k) * rsqrt(D), bf16
// grid (L/64, L/64, NH)
// ---------------------------------------------------------------
__global__ __launch_bounds__(256) void k2_scores(
    const unsigned short* __restrict__ qb, const unsigned short* __restrict__ kb,
    const int* __restrict__ padI32, const int* __restrict__ flags,
    unsigned short* __restrict__ sb) {
    const int k0 = blockIdx.x * 64;
    const int q0 = blockIdx.y * 64;
    const int n  = blockIdx.z;

    float acc[4][4] = {};
    const unsigned short* qn = qb + (size_t)n * L_ * D_;
    const unsigned short* kn = kb + (size_t)n * L_ * D_;
    gemm_bt_core(qn + (size_t)q0 * D_, D_, 1, kn + (size_t)k0 * D_, D_, 1, D_, acc);

    const int tx = threadIdx.x & 15, ty = threadIdx.x >> 4;
    const int bb = n & (B_ - 1);               // n = h*B + b -> b = n % 16
    const float rs = 0.08838834764831845f;     // 1/sqrt(128)
    const bool u8mode = (flags[1] != 0);
    const unsigned char* padU8 = (const unsigned char*)padI32;
    unsigned short* srow = sb + (size_t)n * L_ * L_;
#pragma unroll
    for (int i = 0; i < 4; i++) {
        int qq = q0 + ty * 4 + i;
        size_t mbase = ((size_t)bb * L_ + qq) * L_ + k0 + tx * 4;
        ushort4 sv;
        float s0, s1, s2, s3;
        if (u8mode) {
            s0 = padU8[mbase + 0] ? -1e9f : acc[i][0];
            s1 = padU8[mbase + 1] ? -1e9f : acc[i][1];
            s2 = padU8[mbase + 2] ? -1e9f : acc[i][2];
            s3 = padU8[mbase + 3] ? -1e9f : acc[i][3];
        } else {
            int4 mv = *(const int4*)&padI32[mbase];
            s0 = mv.x ? -1e9f : acc[i][0];
            s1 = mv.y ? -1e9f : acc[i][1];
            s2 = mv.z ? -1e9f : acc[i][2];
            s3 = mv.w ? -1e9f : acc[i][3];
        }
        sv.x = f2bf(s0 * rs); sv.y = f2bf(s1 * rs);
        sv.z = f2bf(s2 * rs); sv.w = f2bf(s3 * rs);
        *(ushort4*)&srow[(size_t)qq * L_ + k0 + tx * 4] = sv;
    }
}

// ---------------------------------------------------------------
// K3: softmax over the QUERY axis (per (n, k) column), in place.
// grid (L/256, NH), 256 threads; thread owns one k column.
// ---------------------------------------------------------------
__global__ __launch_bounds__(256) void k3_softmax(unsigned short* __restrict__ sb) {
    const int n = blockIdx.y;
    const int col = blockIdx.x * 256 + threadIdx.x;
    unsigned short* base = sb + (size_t)n * L_ * L_ + col;

    float m = -INFINITY;
    for (int q = 0; q < L_; q++) m = fmaxf(m, bf2f(base[(size_t)q * L_]));
    float l = 0.f;
    for (int q = 0; q < L_; q++) {
        float e = __expf(bf2f(base[(size_t)q * L_]) - m);
        unsigned short eu = f2bf(e);
        base[(size_t)q * L_] = eu;
        l += bf2f(eu);
    }
    float inv = 1.f / l;
    for (int q = 0; q < L_; q++)
        base[(size_t)q * L_] = f2bf(bf2f(base[(size_t)q * L_]) * inv);
}

// ---------------------------------------------------------------
// K4: att[n,q,d] = sum_k P[n,q,k] * v[n,k,d]   grid (D/64, L/64, NH)
// ---------------------------------------------------------------
__global__ __launch_bounds__(256) void k4_av(
    const unsigned short* __restrict__ sb, const unsigned short* __restrict__ vb,
    unsigned short* __restrict__ att) {
    const int d0 = blockIdx.x * 64;
    const int q0 = blockIdx.y * 64;
    const int n  = blockIdx.z;

    float acc[4][4] = {};
    gemm_bn_core(sb + (size_t)n * L_ * L_ + (size_t)q0 * L_, L_, 1,
                 vb + (size_t)n * L_ * D_ + d0, D_, 1, L_, acc);

    const int tx = threadIdx.x & 15, ty = threadIdx.x >> 4;
#pragma unroll
    for (int i = 0; i < 4; i++) {
        int qq = q0 + ty * 4 + i;
#pragma unroll
        for (int j = 0; j < 4; j++) {
            att[((size_t)n * L_ + qq) * D_ + d0 + tx * 4 + j] = f2bf(acc[i][j]);
        }
    }
}

// ---------------------------------------------------------------
// K5: out = att_view @ W_o^T + b_o.  att read flat as [B*L, H*D]
// (reproduces the torch .view quirk).  grid (D/64, M/64)
// ---------------------------------------------------------------
__global__ __launch_bounds__(256) void k5_out(
    const unsigned short* __restrict__ att, const void* __restrict__ Wo,
    const void* __restrict__ bo, const int* __restrict__ flags,
    void* __restrict__ out) {
    const int dt = flags[0];
    const int n0 = blockIdx.x * 64;   // d_out tile
    const int m0 = blockIdx.y * 64;

    float acc[4][4] = {};
    gemm_bt_core(att + (size_t)m0 * HD_, HD_, 1,
                 dt ? (const void*)((const unsigned short*)Wo + (size_t)n0 * HD_)
                    : (const void*)((const float*)Wo + (size_t)n0 * HD_),
                 HD_, dt, HD_, acc);

    const int tx = threadIdx.x & 15, ty = threadIdx.x >> 4;
#pragma unroll
    for (int i = 0; i < 4; i++) {
        int m = m0 + ty * 4 + i;
#pragma unroll
        for (int j = 0; j < 4; j++) {
            int c = n0 + tx * 4 + j;
            st1(out, (size_t)m * D_ + c, acc[i][j] + ld1(bo, c, dt), dt);
        }
    }
}

// ---------------------------------------------------------------
extern "C" void kernel_launch(void* const* d_in, const int* in_sizes, int n_in,
                              void* d_out, int out_size, void* d_ws, size_t ws_size,
                              hipStream_t stream) {
    (void)in_sizes; (void)n_in; (void)out_size; (void)ws_size;
    const void* x  = d_in[0];
    const void* Wq = d_in[1];
    const void* bq = d_in[2];
    const void* Wk = d_in[3];
    const void* bk = d_in[4];
    const void* Wv = d_in[5];
    const void* bv = d_in[6];
    const void* Wo = d_in[7];
    const void* bo = d_in[8];
    const int* pad = (const int*)d_in[9];

    // workspace layout: flags(256B pad) | q | k | v | s | att  (~128 MiB)
    char* ws = (char*)d_ws;
    int* flags          = (int*)ws;
    unsigned short* qb  = (unsigned short*)(ws + 256);
    unsigned short* kb  = (unsigned short*)(ws + 256 + 16777216);
    unsigned short* vb  = (unsigned short*)(ws + 256 + 2 * 16777216);
    unsigned short* sb  = (unsigned short*)(ws + 256 + 3 * 16777216);
    unsigned short* att = (unsigned short*)(ws + 256 + 3 * 16777216 + 67108864);

    dim3 blk(256);
    hipLaunchKernelGGL(k0_detect, dim3(1), blk, 0, stream,
                       (const unsigned int*)pad, (const unsigned int*)x, flags);
    hipLaunchKernelGGL(k1_proj, dim3(HD_ / 64, M_ / 64, 3), blk, 0, stream,
                       x, Wq, bq, Wk, bk, Wv, bv, flags, qb, kb, vb);
    hipLaunchKernelGGL(k2_scores, dim3(L_ / 64, L_ / 64, NH_), blk, 0, stream,
                       qb, kb, pad, flags, sb);
    hipLaunchKernelGGL(k3_softmax, dim3(L_ / 256, NH_), blk, 0, stream, sb);
    hipLaunchKernelGGL(k4_av, dim3(D_ / 64, L_ / 64, NH_), blk, 0, stream,
                       sb, vb, att);
    hipLaunchKernelGGL(k5_out, dim3(D_ / 64, M_ / 64), blk, 0, stream,
                       att, Wo, bo, flags, d_out);
}

// Round 3
// 253.402 us; speedup vs baseline: 2.6334x; 2.6334x over previous
//
#include <hip/hip_runtime.h>

// Problem constants (B, L, D, H) = (16, 512, 128, 8)
#define B_  16
#define L_  512
#define D_  128
#define H_  8
#define HD_ 1024   // H*D
#define NH_ 128    // H*B
#define M_  8192   // B*L

typedef unsigned short u16;
typedef __attribute__((ext_vector_type(8))) short s16x8;   // 8 bf16 = 4 VGPRs
typedef __attribute__((ext_vector_type(4))) float f32x4;   // MFMA accumulator

// ---------- bf16 helpers (raw ushort representation) ----------
__device__ __forceinline__ float bf2f(u16 u) {
    union { unsigned u; float f; } x; x.u = ((unsigned)u) << 16; return x.f;
}
__device__ __forceinline__ u16 f2bf(float f) {
    unsigned u = __float_as_uint(f);
    return (u16)((u + 0x7FFFu + ((u >> 16) & 1u)) >> 16);   // RNE
}

// ---------------------------------------------------------------
// MFMA bt-core: C(64x64) = A(64xK) @ B(64xK)^T for one wave.
// A, B row-major with leading dims lda/ldb; caller pre-offsets to the
// wave's row/col origin.  Fragment layout (m89/m120-verified):
//   A/B operand: row = lane&15, k = (lane>>4)*8 + j  (16B contiguous)
//   C/D:         col = lane&15, row = (lane>>4)*4 + reg
// ---------------------------------------------------------------
__device__ __forceinline__ void mfma_bt64(const u16* __restrict__ A, int lda,
                                          const u16* __restrict__ B, int ldb,
                                          int K, int lane, f32x4 acc[4][4]) {
    const int mr = lane & 15, quad = lane >> 4;
    for (int k0 = 0; k0 < K; k0 += 32) {
        s16x8 av[4], bv[4];
#pragma unroll
        for (int i = 0; i < 4; i++)
            av[i] = *(const s16x8*)(A + (size_t)(i * 16 + mr) * lda + k0 + quad * 8);
#pragma unroll
        for (int j = 0; j < 4; j++)
            bv[j] = *(const s16x8*)(B + (size_t)(j * 16 + mr) * ldb + k0 + quad * 8);
#pragma unroll
        for (int i = 0; i < 4; i++)
#pragma unroll
            for (int j = 0; j < 4; j++)
                acc[i][j] = __builtin_amdgcn_mfma_f32_16x16x32_bf16(av[i], bv[j], acc[i][j], 0, 0, 0);
    }
}

// ---------------------------------------------------------------
// K0: detect float dtype (fp32 vs packed bf16) + mask dtype (i32 vs u8).
// ---------------------------------------------------------------
__global__ void k0_detect(const unsigned int* __restrict__ pad,
                          const unsigned int* __restrict__ xw,
                          int* __restrict__ flags) {
    __shared__ int sMask, sCnt;
    if (threadIdx.x == 0) { sMask = 0; sCnt = 0; }
    __syncthreads();
    int bad = 0;
#pragma unroll
    for (int i = 0; i < 4; i++) {
        unsigned u = pad[threadIdx.x * 4 + i];
        bad |= (u > 1u) ? 1 : 0;
    }
    int cnt = 0;
#pragma unroll
    for (int i = 0; i < 16; i++) {
        unsigned w = xw[threadIdx.x * 16 + i];
        unsigned e = (w >> 7) & 0xFFu;
        cnt += (e >= 100u && e <= 131u) ? 1 : 0;
    }
    if (bad) atomicOr(&sMask, 1);
    atomicAdd(&sCnt, cnt);
    __syncthreads();
    if (threadIdx.x == 0) {
        flags[0] = (sCnt > 2048) ? 1 : 0;   // 1 => floats are bf16
        flags[1] = sMask;                   // 1 => mask is uint8
    }
}

// ---------------------------------------------------------------
// Kprep_conv: normalize all float inputs to bf16 in ws (copy or convert).
// ---------------------------------------------------------------
#define PREP_TOT 1576064
__global__ __launch_bounds__(256) void kprep_conv(
    const void* x, const void* Wq, const void* bq, const void* Wk, const void* bk,
    const void* Wv, const void* bv, const void* Wo, const void* bo,
    const int* __restrict__ flags,
    u16* xb, u16* Wqb, u16* Wkb, u16* Wvb, u16* Wob,
    u16* bqb, u16* bkb, u16* bvb, u16* bob) {
    int gid = blockIdx.x * 256 + threadIdx.x;
    if (gid >= PREP_TOT) return;
    const int dt = flags[0];
    const void* src; u16* dst; int off;
    if      (gid < 1048576) { src = x;  dst = xb;  off = gid; }
    else if (gid < 1179648) { src = Wq; dst = Wqb; off = gid - 1048576; }
    else if (gid < 1310720) { src = Wk; dst = Wkb; off = gid - 1179648; }
    else if (gid < 1441792) { src = Wv; dst = Wvb; off = gid - 1310720; }
    else if (gid < 1572864) { src = Wo; dst = Wob; off = gid - 1441792; }
    else if (gid < 1573888) { src = bq; dst = bqb; off = gid - 1572864; }
    else if (gid < 1574912) { src = bk; dst = bkb; off = gid - 1573888; }
    else if (gid < 1575936) { src = bv; dst = bvb; off = gid - 1574912; }
    else                    { src = bo; dst = bob; off = gid - 1575936; }
    dst[off] = dt ? ((const u16*)src)[off] : f2bf(((const float*)src)[off]);
}

// ---------------------------------------------------------------
// Kprep_mask: pack pad_mask into bitmask [16][512][16 u32 words].
// ---------------------------------------------------------------
__global__ __launch_bounds__(256) void kprep_mask(const void* __restrict__ pad,
                                                  const int* __restrict__ flags,
                                                  unsigned* __restrict__ mb) {
    int w = blockIdx.x * 256 + threadIdx.x;     // < 131072
    size_t base = (size_t)w * 32;
    unsigned m = 0;
    if (flags[1]) {
        const unsigned char* p = (const unsigned char*)pad;
#pragma unroll
        for (int b = 0; b < 32; b++) m |= (p[base + b] ? 1u : 0u) << b;
    } else {
        const int* p = (const int*)pad;
#pragma unroll
        for (int b = 0; b < 32; b++) m |= (p[base + b] ? 1u : 0u) << b;
    }
    mb[w] = m;
}

// ---------------------------------------------------------------
// K1: QKV projection via MFMA.  y = x @ W^T + b.
// q,k written head-major [n=h*16+bb][l][d]; v written TRANSPOSED [n][d][l].
// grid (8 e-tiles(=head), 64 m-tiles, 3), 256 threads.
// ---------------------------------------------------------------
__global__ __launch_bounds__(256) void k1_proj(
    const u16* __restrict__ xb,
    const u16* __restrict__ Wqb, const u16* __restrict__ Wkb, const u16* __restrict__ Wvb,
    const u16* __restrict__ bqb, const u16* __restrict__ bkb, const u16* __restrict__ bvb,
    u16* __restrict__ qb, u16* __restrict__ kb, u16* __restrict__ vtb) {
    const int h  = blockIdx.x;           // e-tile == head (128 e per head)
    const int m0 = blockIdx.y * 128;
    const int z  = blockIdx.z;
    const u16* W    = (z == 0) ? Wqb : (z == 1) ? Wkb : Wvb;
    const u16* bias = (z == 0) ? bqb : (z == 1) ? bkb : bvb;

    const int lane = threadIdx.x & 63, wave = threadIdx.x >> 6;
    const int wr = wave >> 1, wc = wave & 1;
    const int mr = lane & 15, quad = lane >> 4;

    f32x4 acc[4][4];
#pragma unroll
    for (int i = 0; i < 4; i++)
#pragma unroll
        for (int j = 0; j < 4; j++) acc[i][j] = (f32x4){0.f, 0.f, 0.f, 0.f};

    mfma_bt64(xb + (size_t)(m0 + wr * 64) * D_, D_,
              W + (size_t)(h * 128 + wc * 64) * D_, D_, D_, lane, acc);

    __shared__ __align__(16) u16 T[128][144];
#pragma unroll
    for (int i = 0; i < 4; i++)
#pragma unroll
        for (int j = 0; j < 4; j++) {
            int col = wc * 64 + j * 16 + mr;
            float bv_ = bf2f(bias[h * 128 + col]);
#pragma unroll
            for (int r = 0; r < 4; r++)
                T[wr * 64 + i * 16 + quad * 4 + r][col] = f2bf(acc[i][j][r] + bv_);
        }
    __syncthreads();

    const int bb = m0 >> 9, l0 = m0 & 511;
    const int t = threadIdx.x;
    if (z < 2) {
        u16* out = z ? kb : qb;
        int row = t >> 1, c0 = (t & 1) * 64;
        u16* dst = out + ((size_t)(h * B_ + bb) * L_ + l0 + row) * D_ + c0;
#pragma unroll
        for (int c = 0; c < 64; c += 8)
            *(uint4*)(dst + c) = *(const uint4*)&T[row][c0 + c];
    } else {
        int d = t >> 1, lc0 = (t & 1) * 64;
        u16* dst = vtb + ((size_t)(h * B_ + bb) * D_ + d) * L_ + l0 + lc0;
#pragma unroll
        for (int c = 0; c < 64; c += 8) {
            u16 tmp[8];
#pragma unroll
            for (int s = 0; s < 8; s++) tmp[s] = T[lc0 + c + s][d];
            *(uint4*)(dst + c) = *(const uint4*)tmp;
        }
    }
}

// ---------------------------------------------------------------
// K2: e[n,q,k] = exp( (mask? -1e9 : q.k) * rs ), plus per-column (k)
// inverse sums linv[n,k] = 1/sum_q e.  Block covers ALL q for a 128-wide
// k-strip => column sums without atomics.  grid (4 k-tiles, 128 n).
// ---------------------------------------------------------------
__global__ __launch_bounds__(256) void k2_scores(
    const u16* __restrict__ qb, const u16* __restrict__ kb,
    const unsigned* __restrict__ mbits,
    u16* __restrict__ sb, float* __restrict__ linv) {
    const int k0g = blockIdx.x * 128;
    const int n   = blockIdx.y;
    const int bb  = n & (B_ - 1);
    const int lane = threadIdx.x & 63, wave = threadIdx.x >> 6;
    const int wr = wave >> 1, wc = wave & 1;
    const int mr = lane & 15, quad = lane >> 4;
    const float rs = 0.08838834764831845f;   // 1/sqrt(128)

    __shared__ __align__(16) u16 T[128][144];
    __shared__ float CS[2][128];

    const u16* Abase = qb + (size_t)n * L_ * D_;
    const u16* Bbase = kb + (size_t)n * L_ * D_ + (size_t)(k0g + wc * 64) * D_;

    float colsum[4] = {0.f, 0.f, 0.f, 0.f};
    for (int qt = 0; qt < 4; qt++) {
        f32x4 acc[4][4];
#pragma unroll
        for (int i = 0; i < 4; i++)
#pragma unroll
            for (int j = 0; j < 4; j++) acc[i][j] = (f32x4){0.f, 0.f, 0.f, 0.f};

        mfma_bt64(Abase + (size_t)(qt * 128 + wr * 64) * D_, D_, Bbase, D_, D_, lane, acc);

#pragma unroll
        for (int i = 0; i < 4; i++)
#pragma unroll
            for (int j = 0; j < 4; j++) {
                int kc = k0g + wc * 64 + j * 16 + mr;
#pragma unroll
                for (int r = 0; r < 4; r++) {
                    int ql = wr * 64 + i * 16 + quad * 4 + r;
                    int q  = qt * 128 + ql;
                    unsigned w = mbits[((size_t)(bb << 9) + q) * 16 + (kc >> 5)];
                    float s = ((w >> (kc & 31)) & 1u) ? -1e9f : acc[i][j][r];
                    float e = __expf(s * rs);
                    colsum[j] += e;
                    T[ql][wc * 64 + j * 16 + mr] = f2bf(e);
                }
            }
        __syncthreads();
        {
            int t = threadIdx.x, row = t >> 1, c0 = (t & 1) * 64;
            u16* dst = sb + ((size_t)n * L_ + qt * 128 + row) * L_ + k0g + c0;
#pragma unroll
            for (int c = 0; c < 64; c += 8)
                *(uint4*)(dst + c) = *(const uint4*)&T[row][c0 + c];
        }
        __syncthreads();
    }
    // reduce column sums: over quads (shfl), then over wr pairs (LDS)
#pragma unroll
    for (int j = 0; j < 4; j++) {
        colsum[j] += __shfl_xor(colsum[j], 16);
        colsum[j] += __shfl_xor(colsum[j], 32);
    }
    if (quad == 0) {
#pragma unroll
        for (int j = 0; j < 4; j++) CS[wr][wc * 64 + j * 16 + mr] = colsum[j];
    }
    __syncthreads();
    if (threadIdx.x < 128)
        linv[(size_t)n * L_ + k0g + threadIdx.x] =
            1.0f / (CS[0][threadIdx.x] + CS[1][threadIdx.x]);
}

// ---------------------------------------------------------------
// K3: fold softmax normalization into V^T:  vt[n][d][k] *= linv[n][k].
// 8 elements/thread, grid 4096 x 256.
// ---------------------------------------------------------------
__global__ __launch_bounds__(256) void k3_vscale(u16* __restrict__ vtb,
                                                 const float* __restrict__ linv) {
    int idx = blockIdx.x * 256 + threadIdx.x;      // < 1048576
    int n = idx >> 13;                             // 8192 groups per n
    int rem = idx & 8191;
    int d = rem >> 6;
    int kg = (rem & 63) << 3;
    u16* p = vtb + ((size_t)n * D_ + d) * L_ + kg;
    uint4 v = *(const uint4*)p;
    float lv[8];
    *(float4*)&lv[0] = *(const float4*)(linv + (size_t)n * L_ + kg);
    *(float4*)&lv[4] = *(const float4*)(linv + (size_t)n * L_ + kg + 4);
    u16* u = (u16*)&v;
#pragma unroll
    for (int s = 0; s < 8; s++) u[s] = f2bf(bf2f(u[s]) * lv[s]);
    *(uint4*)p = v;
}

// ---------------------------------------------------------------
// K4: att[n,q,d] = sum_k e[q,k] * vt'[d,k]  (both row-major in k => bt-core)
// grid (4 q-tiles, 128 n).  att aliases qb (flat [n*L+q][D]).
// ---------------------------------------------------------------
__global__ __launch_bounds__(256) void k4_av(
    const u16* __restrict__ sb, const u16* __restrict__ vtb,
    u16* __restrict__ att) {
    const int q0 = blockIdx.x * 128;
    const int n  = blockIdx.y;
    const int lane = threadIdx.x & 63, wave = threadIdx.x >> 6;
    const int wr = wave >> 1, wc = wave & 1;
    const int mr = lane & 15, quad = lane >> 4;

    f32x4 acc[4][4];
#pragma unroll
    for (int i = 0; i < 4; i++)
#pragma unroll
        for (int j = 0; j < 4; j++) acc[i][j] = (f32x4){0.f, 0.f, 0.f, 0.f};

    mfma_bt64(sb + ((size_t)n * L_ + q0 + wr * 64) * L_, L_,
              vtb + ((size_t)n * D_ + wc * 64) * L_, L_, L_, lane, acc);

    __shared__ __align__(16) u16 T[128][144];
#pragma unroll
    for (int i = 0; i < 4; i++)
#pragma unroll
        for (int j = 0; j < 4; j++) {
            int col = wc * 64 + j * 16 + mr;
#pragma unroll
            for (int r = 0; r < 4; r++)
                T[wr * 64 + i * 16 + quad * 4 + r][col] = f2bf(acc[i][j][r]);
        }
    __syncthreads();
    int t = threadIdx.x, row = t >> 1, c0 = (t & 1) * 64;
    u16* dst = att + ((size_t)n * L_ + q0 + row) * D_ + c0;
#pragma unroll
    for (int c = 0; c < 64; c += 8)
        *(uint4*)(dst + c) = *(const uint4*)&T[row][c0 + c];
}

// ---------------------------------------------------------------
// K5: out = att_flat[8192][1024] @ Wo[128][1024]^T + bo.
// BM=64, BN=128, 2 waves (128 threads), grid 128.  dt-switched output.
// ---------------------------------------------------------------
__global__ __launch_bounds__(128) void k5_out(
    const u16* __restrict__ att, const u16* __restrict__ Wob,
    const u16* __restrict__ bob, const int* __restrict__ flags,
    void* __restrict__ out) {
    const int dt = flags[0];
    const int m0 = blockIdx.x * 64;
    const int lane = threadIdx.x & 63, wc = threadIdx.x >> 6;
    const int mr = lane & 15, quad = lane >> 4;

    f32x4 acc[4][4];
#pragma unroll
    for (int i = 0; i < 4; i++)
#pragma unroll
        for (int j = 0; j < 4; j++) acc[i][j] = (f32x4){0.f, 0.f, 0.f, 0.f};

    mfma_bt64(att + (size_t)m0 * HD_, HD_,
              Wob + (size_t)(wc * 64) * HD_, HD_, HD_, lane, acc);

    __shared__ __align__(16) float Tf[64][132];
#pragma unroll
    for (int i = 0; i < 4; i++)
#pragma unroll
        for (int j = 0; j < 4; j++) {
            int col = wc * 64 + j * 16 + mr;
            float bv_ = bf2f(bob[col]);
#pragma unroll
            for (int r = 0; r < 4; r++)
                Tf[i * 16 + quad * 4 + r][col] = acc[i][j][r] + bv_;
        }
    __syncthreads();
    int t = threadIdx.x, row = t >> 1, c0 = (t & 1) * 64;
    size_t base = (size_t)(m0 + row) * D_ + c0;
    if (dt) {
        u16* o = (u16*)out;
#pragma unroll
        for (int c = 0; c < 64; c += 8) {
            u16 tmp[8];
#pragma unroll
            for (int s = 0; s < 8; s++) tmp[s] = f2bf(Tf[row][c0 + c + s]);
            *(uint4*)(o + base + c) = *(const uint4*)tmp;
        }
    } else {
        float* o = (float*)out;
#pragma unroll
        for (int c = 0; c < 64; c += 4)
            *(float4*)(o + base + c) = *(const float4*)&Tf[row][c0 + c];
    }
}

// ---------------------------------------------------------------
extern "C" void kernel_launch(void* const* d_in, const int* in_sizes, int n_in,
                              void* d_out, int out_size, void* d_ws, size_t ws_size,
                              hipStream_t stream) {
    (void)in_sizes; (void)n_in; (void)out_size; (void)ws_size;
    const void* x  = d_in[0];
    const void* Wq = d_in[1]; const void* bq = d_in[2];
    const void* Wk = d_in[3]; const void* bk = d_in[4];
    const void* Wv = d_in[5]; const void* bv = d_in[6];
    const void* Wo = d_in[7]; const void* bo = d_in[8];
    const void* pad = d_in[9];

    char* p = (char*)d_ws;
    auto alloc = [&](size_t bytes) { char* r = p; p += (bytes + 255) & ~(size_t)255; return r; };
    int*  flags = (int*)alloc(256);
    u16*  xb   = (u16*)alloc(2097152);
    u16*  Wqb  = (u16*)alloc(262144);
    u16*  Wkb  = (u16*)alloc(262144);
    u16*  Wvb  = (u16*)alloc(262144);
    u16*  Wob  = (u16*)alloc(262144);
    u16*  bqb  = (u16*)alloc(2048);
    u16*  bkb  = (u16*)alloc(2048);
    u16*  bvb  = (u16*)alloc(2048);
    u16*  bob  = (u16*)alloc(256);
    unsigned* mbits = (unsigned*)alloc(524288);
    float* linv = (float*)alloc(262144);
    u16*  qb   = (u16*)alloc(16777216);
    u16*  kb   = (u16*)alloc(16777216);
    u16*  vtb  = (u16*)alloc(16777216);
    u16*  sb   = (u16*)alloc(67108864);
    u16*  att  = qb;   // alias: qb's last read is K2, att written in K4

    k0_detect<<<1, 256, 0, stream>>>((const unsigned*)pad, (const unsigned*)x, flags);
    kprep_conv<<<(PREP_TOT + 255) / 256, 256, 0, stream>>>(
        x, Wq, bq, Wk, bk, Wv, bv, Wo, bo, flags,
        xb, Wqb, Wkb, Wvb, Wob, bqb, bkb, bvb, bob);
    kprep_mask<<<512, 256, 0, stream>>>(pad, flags, mbits);
    k1_proj<<<dim3(8, 64, 3), 256, 0, stream>>>(
        xb, Wqb, Wkb, Wvb, bqb, bkb, bvb, qb, kb, vtb);
    k2_scores<<<dim3(4, NH_), 256, 0, stream>>>(qb, kb, mbits, sb, linv);
    k3_vscale<<<4096, 256, 0, stream>>>(vtb, linv);
    k4_av<<<dim3(4, NH_), 256, 0, stream>>>(sb, vtb, att);
    k5_out<<<128, 128, 0, stream>>>(att, Wob, bob, flags, d_out);
}